// Round 4
// baseline (181.516 us; speedup 1.0000x reference)
//
#include <hip/hip_runtime.h>
#include <math.h>

#define T 8192
#define M 4096          // half length
#define JS 4104         // padded row stride (elements) for half-spectra
#define B 8
#define CIN 32
#define COUT 32
#define HID 64
#define FT 4

__device__ inline float2 cadd(float2 a, float2 b){ return make_float2(a.x+b.x, a.y+b.y); }
__device__ inline float2 csub(float2 a, float2 b){ return make_float2(a.x-b.x, a.y-b.y); }
__device__ inline float2 cmul(float2 a, float2 b){ return make_float2(a.x*b.x - a.y*b.y, a.x*b.y + a.y*b.x); }
__device__ inline float2 cmulc(float2 a, float2 b){ // a * conj(b)
    return make_float2(a.x*b.x + a.y*b.y, a.y*b.x - a.x*b.y); }
__device__ inline int swz(int p){ return p ^ ((p >> 5) & 31); }
__device__ inline int brev12(int v){ return (int)(__brev((unsigned)v) >> 20); }

__device__ inline float gelu_exact(float x){
    return 0.5f*x*(1.0f + erff(x*0.70710678118654752440f));
}

// tw[k] = e^{-2*pi*i*k/T}, k < 4096
__global__ __launch_bounds__(256) void tw_init(float2* __restrict__ tw){
    int k = blockIdx.x*blockDim.x + threadIdx.x;
    float ang = -6.28318530717958647692f * (float)k / (float)T;
    float s, c;
    sincosf(ang, &s, &c);
    tw[k] = make_float2(c, s);
}

// ---- register-blocked radix-2 groups, 16 pts/thread. Twiddle e^{-i*pi*j/m} = tw[j<<sh],
// sh = 12 - log2(m). Forward (DIF) group: d = 8..1, m = S*d -> SH0 = 9 - log2(S).
template<int S, int SH0>
__device__ inline void dif_group(float2 q[16], int r, const float2* __restrict__ tw){
    #pragma unroll
    for (int st = 0; st < 4; ++st){
        const int d = 8 >> st;
        const int sh = SH0 + st;
        #pragma unroll
        for (int k = 0; k < 8; ++k){
            const int jd = k & (d-1);
            const int lo = ((k & ~(d-1)) << 1) | jd;
            const int hi = lo + d;
            float2 w = tw[(r + S*jd) << sh];
            float2 a = q[lo], b = q[hi];
            q[lo] = cadd(a, b);
            q[hi] = cmul(csub(a, b), w);
        }
    }
}
// Inverse (DIT) group: d = 1..8, m = S*d -> SH0 = 12 - log2(S).
template<int S, int SH0>
__device__ inline void dit_group(float2 q[16], int r, const float2* __restrict__ tw){
    #pragma unroll
    for (int st = 0; st < 4; ++st){
        const int d = 1 << st;
        const int sh = SH0 - st;
        #pragma unroll
        for (int k = 0; k < 8; ++k){
            const int jd = k & (d-1);
            const int lo = ((k & ~(d-1)) << 1) | jd;
            const int hi = lo + d;
            float2 w = tw[(r + S*jd) << sh];
            float2 a = q[lo];
            float2 t2 = cmulc(q[hi], w);
            q[lo] = cadd(a, t2);
            q[hi] = csub(a, t2);
        }
    }
}

__device__ inline void lds_store16(float* sRe, float* sIm, const float2* q, int base, int S){
    #pragma unroll
    for (int l = 0; l < 16; ++l){ int a = swz(base + S*l); sRe[a] = q[l].x; sIm[a] = q[l].y; }
}
__device__ inline void lds_load16(const float* sRe, const float* sIm, float2* q, int base, int S){
    #pragma unroll
    for (int l = 0; l < 16; ++l){ int a = swz(base + S*l); q[l] = make_float2(sRe[a], sIm[a]); }
}

// rfft of a real row of length T via one M-point complex FFT + Hermitian split.
// Output: half-spectrum X[k], k=0..M, stored at dst[j] with k = bitrev12(j) (j<M), dst[M]=X[M].
__global__ __launch_bounds__(256) void rfft_fwd(const float* __restrict__ src,
        const float2* __restrict__ tw, float2* __restrict__ dst){
    __shared__ float sRe[M], sIm[M];
    const int t = threadIdx.x;
    const int sig = blockIdx.x;
    const float2* zp = (const float2*)(src + (size_t)sig*T);   // z[n] = x[2n] + i x[2n+1]
    float2 q[16];
    #pragma unroll
    for (int l = 0; l < 16; ++l) q[l] = zp[t + 256*l];
    dif_group<256,1>(q, t, tw);
    lds_store16(sRe, sIm, q, t, 256);
    __syncthreads();
    {
        const int base = ((t>>4)<<8) | (t&15);
        lds_load16(sRe, sIm, q, base, 16);
        dif_group<16,5>(q, t&15, tw);
        lds_store16(sRe, sIm, q, base, 16);
    }
    __syncthreads();
    {
        const int base = t << 4;
        lds_load16(sRe, sIm, q, base, 1);
        dif_group<1,9>(q, 0, tw);
        lds_store16(sRe, sIm, q, base, 1);
    }
    __syncthreads();
    // Hermitian split: X[k] = E + w_k*O; E=(Z+conj(Zm))/2, O=-i/2*(Z-conj(Zm)), Zm=Z[M-k]
    float2* dp = dst + (size_t)sig*JS;
    #pragma unroll
    for (int l = 0; l < 16; ++l){
        const int j  = t + 256*l;
        const int k  = brev12(j);
        const int j2 = brev12((M - k) & (M-1));
        float2 Z  = make_float2(sRe[swz(j)],  sIm[swz(j)]);
        float2 Zm = make_float2(sRe[swz(j2)], sIm[swz(j2)]);
        float2 E = make_float2(0.5f*(Z.x + Zm.x), 0.5f*(Z.y - Zm.y));
        float2 D = make_float2(Z.x - Zm.x, Z.y + Zm.y);        // Z - conj(Zm)
        float2 O = make_float2(0.5f*D.y, -0.5f*D.x);           // -i/2 * D
        dp[j] = cadd(E, cmul(tw[k], O));
        if (j == 0) dp[M] = make_float2(Z.x - Z.y, 0.0f);      // X[M] = ReZ0 - ImZ0
    }
}

// irfft: half-spectrum (same packed layout) -> real row, fused *1/M-scale... (note: 1/M since
// the half-size inverse FFT of length M reconstructs y with overall 1/M) + bias.
__global__ __launch_bounds__(256) void irfft_out(const float2* __restrict__ Yh,
        const float2* __restrict__ tw, const float* __restrict__ bias, float* __restrict__ out){
    __shared__ float sRe[M], sIm[M];
    const int t = threadIdx.x;
    const int sig = blockIdx.x;
    const float2* yp = Yh + (size_t)sig*JS;
    #pragma unroll
    for (int l = 0; l < 16; ++l){
        const int j = t + 256*l;
        float2 v = yp[j];
        sRe[swz(j)] = v.x; sIm[swz(j)] = v.y;
    }
    float2 yM = yp[M];
    __syncthreads();
    // Hermitian combine (in-place, pair-owned): Z[k] = E + i*O, Z[M-k] = conj(E) + i*conj(O)
    // E = (Y + conj(Ym))/2, O = conj(w_k)*(Y - conj(Ym))/2
    #pragma unroll
    for (int l = 0; l < 16; ++l){
        const int j = t + 256*l;
        const int k = brev12(j);
        if (k <= 2048){
            float2 Ym; int j2 = 0;
            if (k == 0){ Ym = yM; }
            else { j2 = brev12((M - k) & (M-1)); Ym = make_float2(sRe[swz(j2)], sIm[swz(j2)]); }
            float2 Y = make_float2(sRe[swz(j)], sIm[swz(j)]);
            float2 E = make_float2(0.5f*(Y.x + Ym.x), 0.5f*(Y.y - Ym.y));
            float2 D = make_float2(0.5f*(Y.x - Ym.x), 0.5f*(Y.y + Ym.y));   // (Y - conj(Ym))/2
            float2 O = cmulc(D, tw[k]);
            sRe[swz(j)] = E.x - O.y;  sIm[swz(j)] = E.y + O.x;              // Z[k]
            if (k != 0 && k != 2048){
                sRe[swz(j2)] = E.x + O.y;  sIm[swz(j2)] = O.x - E.y;        // Z[M-k]
            }
        }
    }
    __syncthreads();
    float2 q[16];
    {
        const int base = t << 4;
        lds_load16(sRe, sIm, q, base, 1);
        dit_group<1,12>(q, 0, tw);
        lds_store16(sRe, sIm, q, base, 1);
    }
    __syncthreads();
    {
        const int base = ((t>>4)<<8) | (t&15);
        lds_load16(sRe, sIm, q, base, 16);
        dit_group<16,8>(q, t&15, tw);
        lds_store16(sRe, sIm, q, base, 16);
    }
    __syncthreads();
    lds_load16(sRe, sIm, q, t, 256);
    dit_group<256,4>(q, t, tw);
    // q[l] = z[t+256l] natural order; y[2n]=Re z[n], y[2n+1]=Im z[n]
    const float sc = 1.0f/(float)M;
    const float bv = bias[sig & (COUT-1)];
    float2* op = (float2*)(out + (size_t)sig*T);
    #pragma unroll
    for (int l = 0; l < 16; ++l)
        op[t + 256*l] = make_float2(q[l].x*sc + bv, q[l].y*sc + bv);
}

// MLP hidden state H[h*T + t] — 128 blocks x 64 threads for CU coverage
__global__ __launch_bounds__(64) void mlp_hidden(const float* __restrict__ w1, const float* __restrict__ b1,
                           const float* __restrict__ w2, const float* __restrict__ b2,
                           float* __restrict__ H){
    __shared__ float sw1[HID], sb1[HID], sw2[HID*HID], sb2[HID];
    int tid = threadIdx.x;
    for (int i = tid; i < HID; i += blockDim.x){ sw1[i]=w1[i]; sb1[i]=b1[i]; sb2[i]=b2[i]; }
    for (int i = tid; i < HID*HID; i += blockDim.x) sw2[i]=w2[i];
    __syncthreads();
    int t = blockIdx.x*blockDim.x + tid;
    float pos = (float)t / (float)(T-1);
    float h1[HID];
    #pragma unroll
    for (int h = 0; h < HID; ++h) h1[h] = gelu_exact(pos*sw1[h] + sb1[h]);
    for (int h = 0; h < HID; ++h){
        float acc = sb2[h];
        #pragma unroll
        for (int k = 0; k < HID; ++k) acc += h1[k]*sw2[k*HID + h];
        H[h*T + t] = gelu_exact(acc);
    }
}

// Fused filter-spectrum GEMM + channel contraction over packed half-spectra.
// grid = 1025 blocks of 4 j-columns (j <= 4096 valid).
__global__ __launch_bounds__(256) void filt_contract(const float* __restrict__ w3,
        const float* __restrict__ b3, const float2* __restrict__ Hh,
        const float2* __restrict__ Xh, float2* __restrict__ Yh){
    __shared__ float2 Xs[B][CIN][FT];          // 8 KB
    __shared__ float2 FiltS[CIN*COUT][FT+1];   // 40 KB (pad col -> conflict-free reads)
    const int t = threadIdx.x;
    const int f0 = blockIdx.x * FT;
    {
        const float2* xp = Xh + (size_t)t*JS + f0;
        float2 v0 = xp[0], v1 = xp[1], v2 = xp[2], v3 = xp[3];
        const int b = t >> 5, i = t & 31;
        Xs[b][i][0] = v0; Xs[b][i][1] = v1; Xs[b][i][2] = v2; Xs[b][i][3] = v3;
    }
    const int oi0 = t << 2;
    float2 acc[4][FT];
    #pragma unroll
    for (int ii = 0; ii < 4; ++ii)
        #pragma unroll
        for (int f = 0; f < FT; ++f) acc[ii][f] = make_float2(0.f, 0.f);
    for (int h = 0; h < HID; ++h){
        const float4 w4 = *(const float4*)(w3 + (size_t)h*(CIN*COUT) + oi0);
        const float2* hp = Hh + (size_t)h*JS + f0;     // block-uniform -> scalar loads
        float2 h0 = hp[0], h1 = hp[1], h2 = hp[2], h3 = hp[3];
        const float wv[4] = {w4.x, w4.y, w4.z, w4.w};
        #pragma unroll
        for (int ii = 0; ii < 4; ++ii){
            acc[ii][0].x += wv[ii]*h0.x; acc[ii][0].y += wv[ii]*h0.y;
            acc[ii][1].x += wv[ii]*h1.x; acc[ii][1].y += wv[ii]*h1.y;
            acc[ii][2].x += wv[ii]*h2.x; acc[ii][2].y += wv[ii]*h2.y;
            acc[ii][3].x += wv[ii]*h3.x; acc[ii][3].y += wv[ii]*h3.y;
        }
    }
    if (f0 == 0){   // j=0 <-> f=0 (DC): filter spectrum += T*b3
        #pragma unroll
        for (int ii = 0; ii < 4; ++ii)
            acc[ii][0].x += (float)T * b3[oi0 + ii];
    }
    #pragma unroll
    for (int ii = 0; ii < 4; ++ii)
        #pragma unroll
        for (int f = 0; f < FT; ++f)
            FiltS[oi0 + ii][f] = acc[ii][f];
    __syncthreads();
    const int g = t & 1, f2 = (t >> 1) & 3, o2 = t >> 3;
    float2 y[4];
    #pragma unroll
    for (int j = 0; j < 4; ++j) y[j] = make_float2(0.f, 0.f);
    #pragma unroll 4
    for (int i0 = 0; i0 < CIN; ++i0){
        const int i = (i0 + o2) & 31;
        const float2 fv = FiltS[(o2 << 5) | i][f2];
        #pragma unroll
        for (int j = 0; j < 4; ++j){
            const float2 xv = Xs[(g << 2) | j][i][f2];
            y[j].x += xv.x*fv.x - xv.y*fv.y;
            y[j].y += xv.x*fv.y + xv.y*fv.x;
        }
    }
    if (f0 + f2 <= M){
        #pragma unroll
        for (int j = 0; j < 4; ++j){
            const int b = (g << 2) | j;
            Yh[((size_t)(b*COUT + o2))*JS + f0 + f2] = y[j];
        }
    }
}

extern "C" void kernel_launch(void* const* d_in, const int* in_sizes, int n_in,
                              void* d_out, int out_size, void* d_ws, size_t ws_size,
                              hipStream_t stream){
    const float* x    = (const float*)d_in[0];
    const float* w1   = (const float*)d_in[1];
    const float* b1   = (const float*)d_in[2];
    const float* w2   = (const float*)d_in[3];
    const float* b2   = (const float*)d_in[4];
    const float* w3   = (const float*)d_in[5];
    const float* b3   = (const float*)d_in[6];
    const float* bias = (const float*)d_in[7];
    float* out = (float*)d_out;

    // Workspace: Xh 8.5MB | Yh 8.5MB | Hh 2.2MB | H 2MB | tw 32KB  (~24 MB)
    char* ws = (char*)d_ws;
    float2* Xh = (float2*)ws;
    float2* Yh = (float2*)(ws + (size_t)9*1024*1024);
    float2* Hh = (float2*)(ws + (size_t)18*1024*1024);
    float*  H  = (float*) (ws + (size_t)21*1024*1024);
    float2* tws= (float2*)(ws + (size_t)23*1024*1024);

    hipLaunchKernelGGL(tw_init,       dim3(16),    dim3(256), 0, stream, tws);
    hipLaunchKernelGGL(mlp_hidden,    dim3(128),   dim3(64),  0, stream, w1, b1, w2, b2, H);
    hipLaunchKernelGGL(rfft_fwd,      dim3(B*CIN), dim3(256), 0, stream, x, tws, Xh);
    hipLaunchKernelGGL(rfft_fwd,      dim3(HID),   dim3(256), 0, stream, H, tws, Hh);
    hipLaunchKernelGGL(filt_contract, dim3(M/FT + 1), dim3(256), 0, stream, w3, b3, Hh, Xh, Yh);
    hipLaunchKernelGGL(irfft_out,     dim3(B*COUT), dim3(256), 0, stream, Yh, tws, bias, out);
}

// Round 5
// 159.001 us; speedup vs baseline: 1.1416x; 1.1416x over previous
//
#include <hip/hip_runtime.h>
#include <math.h>

#define T 8192
#define M 4096          // half length
#define JS 4104         // padded row stride (elements) for half-spectra
#define B 8
#define CIN 32
#define COUT 32
#define HID 64
#define FT 4

__device__ inline float2 cadd(float2 a, float2 b){ return make_float2(a.x+b.x, a.y+b.y); }
__device__ inline float2 csub(float2 a, float2 b){ return make_float2(a.x-b.x, a.y-b.y); }
__device__ inline float2 cmul(float2 a, float2 b){ return make_float2(a.x*b.x - a.y*b.y, a.x*b.y + a.y*b.x); }
__device__ inline float2 cmulc(float2 a, float2 b){ // a * conj(b)
    return make_float2(a.x*b.x + a.y*b.y, a.y*b.x - a.x*b.y); }
__device__ inline int swz(int p){ return p ^ ((p >> 5) & 31); }
__device__ inline int brev12(int v){ return (int)(__brev((unsigned)v) >> 20); }

__device__ inline float gelu_exact(float x){
    return 0.5f*x*(1.0f + erff(x*0.70710678118654752440f));
}

// tw[k] = e^{-2*pi*i*k/T}, k < 4096
__global__ __launch_bounds__(256) void tw_init(float2* __restrict__ tw){
    int k = blockIdx.x*blockDim.x + threadIdx.x;
    float ang = -6.28318530717958647692f * (float)k / (float)T;
    float s, c;
    sincosf(ang, &s, &c);
    tw[k] = make_float2(c, s);
}

// ---- register-blocked radix-2 groups, 8 pts/thread, 512 threads, 12 stages = 4 groups of 3.
// Twiddle e^{-i*pi*j/m} = tw[j<<sh], sh = 12 - log2(m).
// Forward (DIF) group: local d = 4,2,1; m = S*d -> SH0 = 10 - log2(S).
template<int S, int SH0>
__device__ inline void dif_group8(float2 q[8], int r, const float2* __restrict__ tw){
    #pragma unroll
    for (int st = 0; st < 3; ++st){
        const int d = 4 >> st;
        const int sh = SH0 + st;
        #pragma unroll
        for (int k = 0; k < 4; ++k){
            const int jd = k & (d-1);
            const int lo = ((k & ~(d-1)) << 1) | jd;
            const int hi = lo + d;
            float2 w = tw[(r + S*jd) << sh];
            float2 a = q[lo], b = q[hi];
            q[lo] = cadd(a, b);
            q[hi] = cmul(csub(a, b), w);
        }
    }
}
// Inverse (DIT) group: local d = 1,2,4; m = S*d -> SH0 = 12 - log2(S).
template<int S, int SH0>
__device__ inline void dit_group8(float2 q[8], int r, const float2* __restrict__ tw){
    #pragma unroll
    for (int st = 0; st < 3; ++st){
        const int d = 1 << st;
        const int sh = SH0 - st;
        #pragma unroll
        for (int k = 0; k < 4; ++k){
            const int jd = k & (d-1);
            const int lo = ((k & ~(d-1)) << 1) | jd;
            const int hi = lo + d;
            float2 w = tw[(r + S*jd) << sh];
            float2 a = q[lo];
            float2 t2 = cmulc(q[hi], w);
            q[lo] = cadd(a, t2);
            q[hi] = csub(a, t2);
        }
    }
}

__device__ inline void lds_store8(float* sRe, float* sIm, const float2* q, int base, int S){
    #pragma unroll
    for (int l = 0; l < 8; ++l){ int a = swz(base + S*l); sRe[a] = q[l].x; sIm[a] = q[l].y; }
}
__device__ inline void lds_load8(const float* sRe, const float* sIm, float2* q, int base, int S){
    #pragma unroll
    for (int l = 0; l < 8; ++l){ int a = swz(base + S*l); q[l] = make_float2(sRe[a], sIm[a]); }
}

// rfft of a real row of length T via one M-point complex FFT + Hermitian split.
// Output: half-spectrum X[k], k=0..M, stored at dst[j] with k = bitrev12(j) (j<M), dst[M]=X[M].
__global__ __launch_bounds__(512) void rfft_fwd(const float* __restrict__ src,
        const float2* __restrict__ tw, float2* __restrict__ dst){
    __shared__ float sRe[M], sIm[M];
    const int t = threadIdx.x;
    const int sig = blockIdx.x;
    const float2* zp = (const float2*)(src + (size_t)sig*T);   // z[n] = x[2n] + i x[2n+1]
    float2 q[8];
    #pragma unroll
    for (int l = 0; l < 8; ++l) q[l] = zp[t + 512*l];
    dif_group8<512,1>(q, t, tw);
    lds_store8(sRe, sIm, q, t, 512);
    __syncthreads();
    {
        const int base = ((t>>6)<<9) | (t&63);
        lds_load8(sRe, sIm, q, base, 64);
        dif_group8<64,4>(q, t&63, tw);
        lds_store8(sRe, sIm, q, base, 64);
    }
    __syncthreads();
    {
        const int base = ((t>>3)<<6) | (t&7);
        lds_load8(sRe, sIm, q, base, 8);
        dif_group8<8,7>(q, t&7, tw);
        lds_store8(sRe, sIm, q, base, 8);
    }
    __syncthreads();
    {
        const int base = t << 3;
        lds_load8(sRe, sIm, q, base, 1);
        dif_group8<1,10>(q, 0, tw);
        lds_store8(sRe, sIm, q, base, 1);
    }
    __syncthreads();
    // Hermitian split: X[k] = E + w_k*O; E=(Z+conj(Zm))/2, O=-i/2*(Z-conj(Zm)), Zm=Z[M-k]
    float2* dp = dst + (size_t)sig*JS;
    #pragma unroll
    for (int l = 0; l < 8; ++l){
        const int j  = t + 512*l;
        const int k  = brev12(j);
        const int j2 = brev12((M - k) & (M-1));
        float2 Z  = make_float2(sRe[swz(j)],  sIm[swz(j)]);
        float2 Zm = make_float2(sRe[swz(j2)], sIm[swz(j2)]);
        float2 E = make_float2(0.5f*(Z.x + Zm.x), 0.5f*(Z.y - Zm.y));
        float2 D = make_float2(Z.x - Zm.x, Z.y + Zm.y);        // Z - conj(Zm)
        float2 O = make_float2(0.5f*D.y, -0.5f*D.x);           // -i/2 * D
        dp[j] = cadd(E, cmul(tw[k], O));
        if (j == 0) dp[M] = make_float2(Z.x - Z.y, 0.0f);      // X[M] = ReZ0 - ImZ0
    }
}

// irfft: half-spectrum (packed layout) -> real row, *1/M + bias fused.
__global__ __launch_bounds__(512) void irfft_out(const float2* __restrict__ Yh,
        const float2* __restrict__ tw, const float* __restrict__ bias, float* __restrict__ out){
    __shared__ float sRe[M], sIm[M];
    const int t = threadIdx.x;
    const int sig = blockIdx.x;
    const float2* yp = Yh + (size_t)sig*JS;
    #pragma unroll
    for (int l = 0; l < 8; ++l){
        const int j = t + 512*l;
        float2 v = yp[j];
        sRe[swz(j)] = v.x; sIm[swz(j)] = v.y;
    }
    float2 yM = yp[M];
    __syncthreads();
    // Hermitian combine (pair-owned in-place): Z[k] = E + i*O, Z[M-k] = conj(E) + i*conj(O)
    #pragma unroll
    for (int l = 0; l < 8; ++l){
        const int j = t + 512*l;
        const int k = brev12(j);
        if (k <= 2048){
            float2 Ym; int j2 = 0;
            if (k == 0){ Ym = yM; }
            else { j2 = brev12((M - k) & (M-1)); Ym = make_float2(sRe[swz(j2)], sIm[swz(j2)]); }
            float2 Y = make_float2(sRe[swz(j)], sIm[swz(j)]);
            float2 E = make_float2(0.5f*(Y.x + Ym.x), 0.5f*(Y.y - Ym.y));
            float2 D = make_float2(0.5f*(Y.x - Ym.x), 0.5f*(Y.y + Ym.y));   // (Y - conj(Ym))/2
            float2 O = cmulc(D, tw[k]);
            sRe[swz(j)] = E.x - O.y;  sIm[swz(j)] = E.y + O.x;              // Z[k]
            if (k != 0 && k != 2048){
                sRe[swz(j2)] = E.x + O.y;  sIm[swz(j2)] = O.x - E.y;        // Z[M-k]
            }
        }
    }
    __syncthreads();
    float2 q[8];
    {
        const int base = t << 3;
        lds_load8(sRe, sIm, q, base, 1);
        dit_group8<1,12>(q, 0, tw);
        lds_store8(sRe, sIm, q, base, 1);
    }
    __syncthreads();
    {
        const int base = ((t>>3)<<6) | (t&7);
        lds_load8(sRe, sIm, q, base, 8);
        dit_group8<8,9>(q, t&7, tw);
        lds_store8(sRe, sIm, q, base, 8);
    }
    __syncthreads();
    {
        const int base = ((t>>6)<<9) | (t&63);
        lds_load8(sRe, sIm, q, base, 64);
        dit_group8<64,6>(q, t&63, tw);
        lds_store8(sRe, sIm, q, base, 64);
    }
    __syncthreads();
    lds_load8(sRe, sIm, q, t, 512);
    dit_group8<512,3>(q, t, tw);        // final group fused to output
    const float sc = 1.0f/(float)M;
    const float bv = bias[sig & (COUT-1)];
    float2* op = (float2*)(out + (size_t)sig*T);
    #pragma unroll
    for (int l = 0; l < 8; ++l)
        op[t + 512*l] = make_float2(q[l].x*sc + bv, q[l].y*sc + bv);
}

// MLP hidden state H[h*T + t]. Block = 32 positions; h1 staged in LDS; 8 acc ILP in phase 2.
#define TB 32
__global__ __launch_bounds__(256) void mlp_hidden(const float* __restrict__ w1, const float* __restrict__ b1,
                           const float* __restrict__ w2, const float* __restrict__ b2,
                           float* __restrict__ H){
    __shared__ float sw1[HID], sb1[HID], sw2[HID*HID], sb2[HID];
    __shared__ float h1s[TB][HID+1];
    const int tid = threadIdx.x;
    for (int i = tid; i < HID; i += 256){ sw1[i]=w1[i]; sb1[i]=b1[i]; sb2[i]=b2[i]; }
    for (int i = tid; i < HID*HID; i += 256) sw2[i]=w2[i];
    __syncthreads();
    const int t0 = blockIdx.x * TB;
    // phase 1: TB*HID layer-1 activations, 8 per thread
    for (int e = tid; e < TB*HID; e += 256){
        const int tl = e & (TB-1), h = e >> 5;
        const float pos = (float)(t0 + tl) / (float)(T-1);
        h1s[tl][h] = gelu_exact(pos*sw1[h] + sb1[h]);
    }
    __syncthreads();
    // phase 2: thread = (tl, hg); 8 h-outputs each
    const int tl = tid & (TB-1), hg = tid >> 5;   // hg 0..7
    float acc[8];
    #pragma unroll
    for (int u = 0; u < 8; ++u) acc[u] = sb2[hg*8 + u];
    for (int k = 0; k < HID; ++k){
        const float hv = h1s[tl][k];
        const float4 wa = *(const float4*)&sw2[k*HID + hg*8];
        const float4 wb = *(const float4*)&sw2[k*HID + hg*8 + 4];
        acc[0] += hv*wa.x; acc[1] += hv*wa.y; acc[2] += hv*wa.z; acc[3] += hv*wa.w;
        acc[4] += hv*wb.x; acc[5] += hv*wb.y; acc[6] += hv*wb.z; acc[7] += hv*wb.w;
    }
    #pragma unroll
    for (int u = 0; u < 8; ++u)
        H[(size_t)(hg*8 + u)*T + t0 + tl] = gelu_exact(acc[u]);
}

// Fused filter-spectrum GEMM + channel contraction over packed half-spectra.
// grid = (1025, 2): 4 j-columns x o-half (16 of 32 outputs). 24 KB LDS -> 6 blocks/CU.
__global__ __launch_bounds__(256) void filt_contract(const float* __restrict__ w3,
        const float* __restrict__ b3, const float2* __restrict__ Hh,
        const float2* __restrict__ Xh, float2* __restrict__ Yh){
    __shared__ float2 Xs[B][CIN][FT];          // 8 KB
    __shared__ float2 FiltS[512][FT];          // 16 KB  [local oi][f] -> conflict-free both ways
    const int t = threadIdx.x;
    const int f0 = blockIdx.x * FT;
    const int oh = blockIdx.y;                 // o-half: o in [oh*16, oh*16+16)
    {
        const float2* xp = Xh + (size_t)t*JS + f0;
        float2 v0 = xp[0], v1 = xp[1], v2 = xp[2], v3 = xp[3];
        const int b = t >> 5, i = t & 31;
        Xs[b][i][0] = v0; Xs[b][i][1] = v1; Xs[b][i][2] = v2; Xs[b][i][3] = v3;
    }
    // phase A: 2 local oi per thread (local oi = 2t, 2t+1; global oi = oh*512 + local)
    const int oiL = t << 1;
    const int oiG = oh*512 + oiL;
    float2 acc[2][FT];
    #pragma unroll
    for (int ii = 0; ii < 2; ++ii)
        #pragma unroll
        for (int f = 0; f < FT; ++f) acc[ii][f] = make_float2(0.f, 0.f);
    for (int h = 0; h < HID; ++h){
        const float2 w2v = *(const float2*)(w3 + (size_t)h*(CIN*COUT) + oiG);  // coalesced
        const float2* hp = Hh + (size_t)h*JS + f0;                             // wave-uniform -> scalar
        float2 h0 = hp[0], h1 = hp[1], h2 = hp[2], h3 = hp[3];
        const float wv[2] = {w2v.x, w2v.y};
        #pragma unroll
        for (int ii = 0; ii < 2; ++ii){
            acc[ii][0].x += wv[ii]*h0.x; acc[ii][0].y += wv[ii]*h0.y;
            acc[ii][1].x += wv[ii]*h1.x; acc[ii][1].y += wv[ii]*h1.y;
            acc[ii][2].x += wv[ii]*h2.x; acc[ii][2].y += wv[ii]*h2.y;
            acc[ii][3].x += wv[ii]*h3.x; acc[ii][3].y += wv[ii]*h3.y;
        }
    }
    if (f0 == 0){   // DC: filter spectrum += T*b3
        #pragma unroll
        for (int ii = 0; ii < 2; ++ii)
            acc[ii][0].x += (float)T * b3[oiG + ii];
    }
    // contiguous 64B store per thread -> conflict-free
    #pragma unroll
    for (int ii = 0; ii < 2; ++ii)
        #pragma unroll
        for (int f = 0; f < FT; ++f)
            FiltS[oiL + ii][f] = acc[ii][f];
    __syncthreads();
    // phase B: thread = (o2 = t>>4 in 0..15, f2 = (t>>2)&3, g = t&3); 2 batches each (b = 2g+j)
    const int o2 = t >> 4, f2 = (t >> 2) & 3, g = t & 3;
    float2 y[2];
    y[0] = make_float2(0.f, 0.f); y[1] = make_float2(0.f, 0.f);
    #pragma unroll 4
    for (int i0 = 0; i0 < CIN; ++i0){
        const int i = (i0 + o2) & 31;           // rotation: unique address per bank
        const float2 fv = FiltS[(o2 << 5) | i][f2];
        #pragma unroll
        for (int j = 0; j < 2; ++j){
            const float2 xv = Xs[(g << 1) | j][i][f2];
            y[j].x += xv.x*fv.x - xv.y*fv.y;
            y[j].y += xv.x*fv.y + xv.y*fv.x;
        }
    }
    if (f0 + f2 <= M){
        #pragma unroll
        for (int j = 0; j < 2; ++j){
            const int b = (g << 1) | j;
            const int o = oh*16 + o2;
            Yh[((size_t)(b*COUT + o))*JS + f0 + f2] = y[j];
        }
    }
}

extern "C" void kernel_launch(void* const* d_in, const int* in_sizes, int n_in,
                              void* d_out, int out_size, void* d_ws, size_t ws_size,
                              hipStream_t stream){
    const float* x    = (const float*)d_in[0];
    const float* w1   = (const float*)d_in[1];
    const float* b1   = (const float*)d_in[2];
    const float* w2   = (const float*)d_in[3];
    const float* b2   = (const float*)d_in[4];
    const float* w3   = (const float*)d_in[5];
    const float* b3   = (const float*)d_in[6];
    const float* bias = (const float*)d_in[7];
    float* out = (float*)d_out;

    // Workspace: Xh 8.5MB | Yh 8.5MB | Hh 2.2MB | H 2MB | tw 32KB  (~24 MB)
    char* ws = (char*)d_ws;
    float2* Xh = (float2*)ws;
    float2* Yh = (float2*)(ws + (size_t)9*1024*1024);
    float2* Hh = (float2*)(ws + (size_t)18*1024*1024);
    float*  H  = (float*) (ws + (size_t)21*1024*1024);
    float2* tws= (float2*)(ws + (size_t)23*1024*1024);

    hipLaunchKernelGGL(tw_init,       dim3(16),    dim3(256), 0, stream, tws);
    hipLaunchKernelGGL(mlp_hidden,    dim3(T/TB),  dim3(256), 0, stream, w1, b1, w2, b2, H);
    hipLaunchKernelGGL(rfft_fwd,      dim3(B*CIN), dim3(512), 0, stream, x, tws, Xh);
    hipLaunchKernelGGL(rfft_fwd,      dim3(HID),   dim3(512), 0, stream, H, tws, Hh);
    hipLaunchKernelGGL(filt_contract, dim3(M/FT + 1, 2), dim3(256), 0, stream, w3, b3, Hh, Xh, Yh);
    hipLaunchKernelGGL(irfft_out,     dim3(B*COUT), dim3(512), 0, stream, Yh, tws, bias, out);
}

// Round 6
// 147.823 us; speedup vs baseline: 1.2279x; 1.0756x over previous
//
#include <hip/hip_runtime.h>
#include <math.h>

#define T 8192
#define M 4096          // half length
#define JS 4104         // padded row stride (elements) for half-spectra
#define B 8
#define CIN 32
#define COUT 32
#define HID 64
#define FT 4

__device__ inline float2 cadd(float2 a, float2 b){ return make_float2(a.x+b.x, a.y+b.y); }
__device__ inline float2 csub(float2 a, float2 b){ return make_float2(a.x-b.x, a.y-b.y); }
__device__ inline float2 cmul(float2 a, float2 b){ return make_float2(a.x*b.x - a.y*b.y, a.x*b.y + a.y*b.x); }
__device__ inline float2 cmulc(float2 a, float2 b){ // a * conj(b)
    return make_float2(a.x*b.x + a.y*b.y, a.y*b.x - a.x*b.y); }
__device__ inline int swz(int p){ return p ^ ((p >> 5) & 31); }
__device__ inline int brev12(int v){ return (int)(__brev((unsigned)v) >> 20); }

__device__ inline float gelu_exact(float x){
    return 0.5f*x*(1.0f + erff(x*0.70710678118654752440f));
}

// tw[k] = e^{-2*pi*i*k/T}, k < 4096
__global__ __launch_bounds__(256) void tw_init(float2* __restrict__ tw){
    int k = blockIdx.x*blockDim.x + threadIdx.x;
    float ang = -6.28318530717958647692f * (float)k / (float)T;
    float s, c;
    sincosf(ang, &s, &c);
    tw[k] = make_float2(c, s);
}

// ---- register-blocked radix-2 groups, 8 pts/thread, 512 threads, 12 stages = 4 groups of 3.
// Twiddle e^{-i*pi*j/m} = tw[j<<sh], sh = 12 - log2(m).
template<int S, int SH0>
__device__ inline void dif_group8(float2 q[8], int r, const float2* __restrict__ tw){
    #pragma unroll
    for (int st = 0; st < 3; ++st){
        const int d = 4 >> st;
        const int sh = SH0 + st;
        #pragma unroll
        for (int k = 0; k < 4; ++k){
            const int jd = k & (d-1);
            const int lo = ((k & ~(d-1)) << 1) | jd;
            const int hi = lo + d;
            float2 w = tw[(r + S*jd) << sh];
            float2 a = q[lo], b = q[hi];
            q[lo] = cadd(a, b);
            q[hi] = cmul(csub(a, b), w);
        }
    }
}
template<int S, int SH0>
__device__ inline void dit_group8(float2 q[8], int r, const float2* __restrict__ tw){
    #pragma unroll
    for (int st = 0; st < 3; ++st){
        const int d = 1 << st;
        const int sh = SH0 - st;
        #pragma unroll
        for (int k = 0; k < 4; ++k){
            const int jd = k & (d-1);
            const int lo = ((k & ~(d-1)) << 1) | jd;
            const int hi = lo + d;
            float2 w = tw[(r + S*jd) << sh];
            float2 a = q[lo];
            float2 t2 = cmulc(q[hi], w);
            q[lo] = cadd(a, t2);
            q[hi] = csub(a, t2);
        }
    }
}

// AoS float2 LDS + swz: b64 DS ops (half the instruction count of SoA b32)
__device__ inline void lds_store8(float2* sc, const float2* q, int base, int S){
    #pragma unroll
    for (int l = 0; l < 8; ++l) sc[swz(base + S*l)] = q[l];
}
__device__ inline void lds_load8(const float2* sc, float2* q, int base, int S){
    #pragma unroll
    for (int l = 0; l < 8; ++l) q[l] = sc[swz(base + S*l)];
}

// rfft of a real row (length T) via M-point complex FFT + Hermitian split.
// Merged launch: sig<256 -> x rows -> Xh; sig>=256 -> H rows -> Hh.
__global__ __launch_bounds__(512) void rfft_all(const float* __restrict__ x,
        const float* __restrict__ H, const float2* __restrict__ tw,
        float2* __restrict__ Xh, float2* __restrict__ Hh){
    __shared__ float2 sc[M];
    const int t = threadIdx.x;
    const int sig = blockIdx.x;
    const float* srow;
    float2* dp;
    if (sig < B*CIN){ srow = x + (size_t)sig*T;        dp = Xh + (size_t)sig*JS; }
    else            { srow = H + (size_t)(sig-B*CIN)*T; dp = Hh + (size_t)(sig-B*CIN)*JS; }
    const float2* zp = (const float2*)srow;            // z[n] = x[2n] + i x[2n+1]
    float2 q[8];
    #pragma unroll
    for (int l = 0; l < 8; ++l) q[l] = zp[t + 512*l];
    dif_group8<512,1>(q, t, tw);
    lds_store8(sc, q, t, 512);
    __syncthreads();
    {
        const int base = ((t>>6)<<9) | (t&63);
        lds_load8(sc, q, base, 64);
        dif_group8<64,4>(q, t&63, tw);
        lds_store8(sc, q, base, 64);
    }
    __syncthreads();
    {
        const int base = ((t>>3)<<6) | (t&7);
        lds_load8(sc, q, base, 8);
        dif_group8<8,7>(q, t&7, tw);
        lds_store8(sc, q, base, 8);
    }
    __syncthreads();
    {
        const int base = t << 3;
        lds_load8(sc, q, base, 1);
        dif_group8<1,10>(q, 0, tw);
        lds_store8(sc, q, base, 1);
    }
    __syncthreads();
    // Hermitian split: X[k] = E + w_k*O; Zm = Z[M-k]
    #pragma unroll
    for (int l = 0; l < 8; ++l){
        const int j  = t + 512*l;
        const int k  = brev12(j);
        const int j2 = brev12((M - k) & (M-1));
        float2 Z  = sc[swz(j)];
        float2 Zm = sc[swz(j2)];
        float2 E = make_float2(0.5f*(Z.x + Zm.x), 0.5f*(Z.y - Zm.y));
        float2 D = make_float2(Z.x - Zm.x, Z.y + Zm.y);        // Z - conj(Zm)
        float2 O = make_float2(0.5f*D.y, -0.5f*D.x);           // -i/2 * D
        dp[j] = cadd(E, cmul(tw[k], O));
        if (j == 0) dp[M] = make_float2(Z.x - Z.y, 0.0f);      // X[M] = ReZ0 - ImZ0
    }
}

// irfft: half-spectrum (packed layout) -> real row, *1/M + bias fused.
__global__ __launch_bounds__(512) void irfft_out(const float2* __restrict__ Yh,
        const float2* __restrict__ tw, const float* __restrict__ bias, float* __restrict__ out){
    __shared__ float2 sc[M];
    const int t = threadIdx.x;
    const int sig = blockIdx.x;
    const float2* yp = Yh + (size_t)sig*JS;
    #pragma unroll
    for (int l = 0; l < 8; ++l){
        const int j = t + 512*l;
        sc[swz(j)] = yp[j];
    }
    float2 yM = yp[M];
    __syncthreads();
    // Hermitian combine (pair-owned in-place): Z[k] = E + i*O, Z[M-k] = conj(E) + i*conj(O)
    #pragma unroll
    for (int l = 0; l < 8; ++l){
        const int j = t + 512*l;
        const int k = brev12(j);
        if (k <= 2048){
            float2 Ym; int j2 = 0;
            if (k == 0){ Ym = yM; }
            else { j2 = brev12((M - k) & (M-1)); Ym = sc[swz(j2)]; }
            float2 Y = sc[swz(j)];
            float2 E = make_float2(0.5f*(Y.x + Ym.x), 0.5f*(Y.y - Ym.y));
            float2 D = make_float2(0.5f*(Y.x - Ym.x), 0.5f*(Y.y + Ym.y));   // (Y - conj(Ym))/2
            float2 O = cmulc(D, tw[k]);
            sc[swz(j)] = make_float2(E.x - O.y, E.y + O.x);                 // Z[k]
            if (k != 0 && k != 2048){
                sc[swz(j2)] = make_float2(E.x + O.y, O.x - E.y);            // Z[M-k]
            }
        }
    }
    __syncthreads();
    float2 q[8];
    {
        const int base = t << 3;
        lds_load8(sc, q, base, 1);
        dit_group8<1,12>(q, 0, tw);
        lds_store8(sc, q, base, 1);
    }
    __syncthreads();
    {
        const int base = ((t>>3)<<6) | (t&7);
        lds_load8(sc, q, base, 8);
        dit_group8<8,9>(q, t&7, tw);
        lds_store8(sc, q, base, 8);
    }
    __syncthreads();
    {
        const int base = ((t>>6)<<9) | (t&63);
        lds_load8(sc, q, base, 64);
        dit_group8<64,6>(q, t&63, tw);
        lds_store8(sc, q, base, 64);
    }
    __syncthreads();
    lds_load8(sc, q, t, 512);
    dit_group8<512,3>(q, t, tw);        // final group fused to output
    const float scv = 1.0f/(float)M;
    const float bv = bias[sig & (COUT-1)];
    float2* op = (float2*)(out + (size_t)sig*T);
    #pragma unroll
    for (int l = 0; l < 8; ++l)
        op[t + 512*l] = make_float2(q[l].x*scv + bv, q[l].y*scv + bv);
}

// MLP hidden state H[h*T + t]. Block = 32 positions; h1 staged in LDS; 8 acc ILP in phase 2.
#define TB 32
__global__ __launch_bounds__(256) void mlp_hidden(const float* __restrict__ w1, const float* __restrict__ b1,
                           const float* __restrict__ w2, const float* __restrict__ b2,
                           float* __restrict__ H){
    __shared__ float sw1[HID], sb1[HID], sw2[HID*HID], sb2[HID];
    __shared__ float h1s[TB][HID+1];
    const int tid = threadIdx.x;
    for (int i = tid; i < HID; i += 256){ sw1[i]=w1[i]; sb1[i]=b1[i]; sb2[i]=b2[i]; }
    for (int i = tid; i < HID*HID; i += 256) sw2[i]=w2[i];
    __syncthreads();
    const int t0 = blockIdx.x * TB;
    for (int e = tid; e < TB*HID; e += 256){
        const int tl = e & (TB-1), h = e >> 5;
        const float pos = (float)(t0 + tl) / (float)(T-1);
        h1s[tl][h] = gelu_exact(pos*sw1[h] + sb1[h]);
    }
    __syncthreads();
    const int tl = tid & (TB-1), hg = tid >> 5;   // hg 0..7
    float acc[8];
    #pragma unroll
    for (int u = 0; u < 8; ++u) acc[u] = sb2[hg*8 + u];
    for (int k = 0; k < HID; ++k){
        const float hv = h1s[tl][k];
        const float4 wa = *(const float4*)&sw2[k*HID + hg*8];
        const float4 wb = *(const float4*)&sw2[k*HID + hg*8 + 4];
        acc[0] += hv*wa.x; acc[1] += hv*wa.y; acc[2] += hv*wa.z; acc[3] += hv*wa.w;
        acc[4] += hv*wb.x; acc[5] += hv*wb.y; acc[6] += hv*wb.z; acc[7] += hv*wb.w;
    }
    #pragma unroll
    for (int u = 0; u < 8; ++u)
        H[(size_t)(hg*8 + u)*T + t0 + tl] = gelu_exact(acc[u]);
}

// Fused filter-spectrum GEMM + channel contraction over packed half-spectra.
// grid = (1025, 2): 4 j-columns x o-half. Conflict-engineered SoA LDS (~25.5 KB -> 6 blocks/CU).
__global__ __launch_bounds__(256) void filt_contract(const float* __restrict__ w3,
        const float* __restrict__ b3, const float2* __restrict__ Hh,
        const float2* __restrict__ Xh, float2* __restrict__ Yh){
    __shared__ float XsRe[CIN][FT][B+1];    // [i][f][b] pad 9: phase-B bank 4i+9f+b -> free
    __shared__ float XsIm[CIN][FT][B+1];
    __shared__ float FltRe[FT][16][33];     // [f][oL][i] pad 33: stores & reads <=2-way (free)
    __shared__ float FltIm[FT][16][33];
    const int t = threadIdx.x;
    const int f0 = blockIdx.x * FT;
    const int oh = blockIdx.y;              // o-half: o in [oh*16, oh*16+16)
    // stage X tile: sig = t (0..255 = B*CIN); two float4 loads (16B aligned)
    {
        const float4* xp4 = (const float4*)(Xh + (size_t)t*JS + f0);
        float4 u0 = xp4[0], u1 = xp4[1];
        const int b = t >> 5, i = t & 31;
        XsRe[i][0][b] = u0.x; XsIm[i][0][b] = u0.y;
        XsRe[i][1][b] = u0.z; XsIm[i][1][b] = u0.w;
        XsRe[i][2][b] = u1.x; XsIm[i][2][b] = u1.y;
        XsRe[i][3][b] = u1.z; XsIm[i][3][b] = u1.w;
    }
    // phase A: 2 oi per thread (oiG = oh*512 + 2t, 2t+1)
    const int oiG = oh*512 + (t << 1);
    float2 acc[2][FT];
    #pragma unroll
    for (int ii = 0; ii < 2; ++ii)
        #pragma unroll
        for (int f = 0; f < FT; ++f) acc[ii][f] = make_float2(0.f, 0.f);
    #pragma unroll 4
    for (int h = 0; h < HID; ++h){
        const float2 w2v = *(const float2*)(w3 + (size_t)h*(CIN*COUT) + oiG);  // coalesced
        const float2* hp = Hh + (size_t)h*JS + f0;                             // block-uniform
        float2 h0 = hp[0], h1 = hp[1], h2 = hp[2], h3 = hp[3];
        const float wv[2] = {w2v.x, w2v.y};
        #pragma unroll
        for (int ii = 0; ii < 2; ++ii){
            acc[ii][0].x += wv[ii]*h0.x; acc[ii][0].y += wv[ii]*h0.y;
            acc[ii][1].x += wv[ii]*h1.x; acc[ii][1].y += wv[ii]*h1.y;
            acc[ii][2].x += wv[ii]*h2.x; acc[ii][2].y += wv[ii]*h2.y;
            acc[ii][3].x += wv[ii]*h3.x; acc[ii][3].y += wv[ii]*h3.y;
        }
    }
    if (f0 == 0){   // DC: filter spectrum += T*b3
        #pragma unroll
        for (int ii = 0; ii < 2; ++ii)
            acc[ii][0].x += (float)T * b3[oiG + ii];
    }
    {
        const int oL = t >> 4;
        const int ib = (t & 15) << 1;
        #pragma unroll
        for (int ii = 0; ii < 2; ++ii)
            #pragma unroll
            for (int f = 0; f < FT; ++f){
                FltRe[f][oL][ib + ii] = acc[ii][f].x;
                FltIm[f][oL][ib + ii] = acc[ii][f].y;
            }
    }
    __syncthreads();
    // phase B: thread = (o2 = t>>4, f2 = (t>>2)&3, g = t&3); batches b = 2g+j
    const int o2 = t >> 4, f2 = (t >> 2) & 3, g = t & 3;
    float2 y[2];
    y[0] = make_float2(0.f, 0.f); y[1] = make_float2(0.f, 0.f);
    #pragma unroll 8
    for (int i0 = 0; i0 < CIN; ++i0){
        const float2 fv = make_float2(FltRe[f2][o2][i0], FltIm[f2][o2][i0]);
        #pragma unroll
        for (int j = 0; j < 2; ++j){
            const int b = (g << 1) | j;
            const float2 xv = make_float2(XsRe[i0][f2][b], XsIm[i0][f2][b]);
            y[j].x += xv.x*fv.x - xv.y*fv.y;
            y[j].y += xv.x*fv.y + xv.y*fv.x;
        }
    }
    if (f0 + f2 <= M){
        #pragma unroll
        for (int j = 0; j < 2; ++j){
            const int b = (g << 1) | j;
            const int o = oh*16 + o2;
            Yh[((size_t)(b*COUT + o))*JS + f0 + f2] = y[j];
        }
    }
}

extern "C" void kernel_launch(void* const* d_in, const int* in_sizes, int n_in,
                              void* d_out, int out_size, void* d_ws, size_t ws_size,
                              hipStream_t stream){
    const float* x    = (const float*)d_in[0];
    const float* w1   = (const float*)d_in[1];
    const float* b1   = (const float*)d_in[2];
    const float* w2   = (const float*)d_in[3];
    const float* b2   = (const float*)d_in[4];
    const float* w3   = (const float*)d_in[5];
    const float* b3   = (const float*)d_in[6];
    const float* bias = (const float*)d_in[7];
    float* out = (float*)d_out;

    // Workspace: Xh 8.5MB | Yh 8.5MB | Hh 2.2MB | H 2MB | tw 32KB  (~24 MB)
    char* ws = (char*)d_ws;
    float2* Xh = (float2*)ws;
    float2* Yh = (float2*)(ws + (size_t)9*1024*1024);
    float2* Hh = (float2*)(ws + (size_t)18*1024*1024);
    float*  H  = (float*) (ws + (size_t)21*1024*1024);
    float2* tws= (float2*)(ws + (size_t)23*1024*1024);

    hipLaunchKernelGGL(tw_init,       dim3(16),        dim3(256), 0, stream, tws);
    hipLaunchKernelGGL(mlp_hidden,    dim3(T/TB),      dim3(256), 0, stream, w1, b1, w2, b2, H);
    hipLaunchKernelGGL(rfft_all,      dim3(B*CIN+HID), dim3(512), 0, stream, x, H, tws, Xh, Hh);
    hipLaunchKernelGGL(filt_contract, dim3(M/FT + 1, 2), dim3(256), 0, stream, w3, b3, Hh, Xh, Yh);
    hipLaunchKernelGGL(irfft_out,     dim3(B*COUT),    dim3(512), 0, stream, Yh, tws, bias, out);
}

// Round 7
// 143.807 us; speedup vs baseline: 1.2622x; 1.0279x over previous
//
#include <hip/hip_runtime.h>
#include <math.h>

#define T 8192
#define M 4096          // half length
#define JS 4104         // padded row stride (elements) for half-spectra
#define B 8
#define CIN 32
#define COUT 32
#define HID 64
#define FT 4

__device__ inline float2 cadd(float2 a, float2 b){ return make_float2(a.x+b.x, a.y+b.y); }
__device__ inline float2 csub(float2 a, float2 b){ return make_float2(a.x-b.x, a.y-b.y); }
__device__ inline float2 cmul(float2 a, float2 b){ return make_float2(a.x*b.x - a.y*b.y, a.x*b.y + a.y*b.x); }
__device__ inline float2 cmulc(float2 a, float2 b){ // a * conj(b)
    return make_float2(a.x*b.x + a.y*b.y, a.y*b.x - a.x*b.y); }
__device__ inline int swz(int p){ return p ^ ((p >> 5) & 31); }
__device__ inline int brev12(int v){ return (int)(__brev((unsigned)v) >> 20); }

__device__ inline float gelu_exact(float x){
    return 0.5f*x*(1.0f + erff(x*0.70710678118654752440f));
}

// ---- register-blocked radix-2 groups, 8 pts/thread, 512 threads, 12 stages = 4 groups of 3.
// Twiddle e^{-i*pi*j/m} = tw[j<<sh], sh = 12 - log2(m).
template<int S, int SH0>
__device__ inline void dif_group8(float2 q[8], int r, const float2* __restrict__ tw){
    #pragma unroll
    for (int st = 0; st < 3; ++st){
        const int d = 4 >> st;
        const int sh = SH0 + st;
        #pragma unroll
        for (int k = 0; k < 4; ++k){
            const int jd = k & (d-1);
            const int lo = ((k & ~(d-1)) << 1) | jd;
            const int hi = lo + d;
            float2 w = tw[(r + S*jd) << sh];
            float2 a = q[lo], b = q[hi];
            q[lo] = cadd(a, b);
            q[hi] = cmul(csub(a, b), w);
        }
    }
}
template<int S, int SH0>
__device__ inline void dit_group8(float2 q[8], int r, const float2* __restrict__ tw){
    #pragma unroll
    for (int st = 0; st < 3; ++st){
        const int d = 1 << st;
        const int sh = SH0 - st;
        #pragma unroll
        for (int k = 0; k < 4; ++k){
            const int jd = k & (d-1);
            const int lo = ((k & ~(d-1)) << 1) | jd;
            const int hi = lo + d;
            float2 w = tw[(r + S*jd) << sh];
            float2 a = q[lo];
            float2 t2 = cmulc(q[hi], w);
            q[lo] = cadd(a, t2);
            q[hi] = csub(a, t2);
        }
    }
}

// AoS float2 LDS + swz: b64 DS ops
__device__ inline void lds_store8(float2* sc, const float2* q, int base, int S){
    #pragma unroll
    for (int l = 0; l < 8; ++l) sc[swz(base + S*l)] = q[l];
}
__device__ inline void lds_load8(const float2* sc, float2* q, int base, int S){
    #pragma unroll
    for (int l = 0; l < 8; ++l) q[l] = sc[swz(base + S*l)];
}

// rfft of a real row (length T) via M-point complex FFT + Hermitian split.
// Merged launch: sig<256 -> x rows -> Xh; sig>=256 -> H rows -> Hh.
// Barriers: 2 (groups at S=64,8,1 are wave-local: 512-pt chunk per wave64).
__global__ __launch_bounds__(512) void rfft_all(const float* __restrict__ x,
        const float* __restrict__ H, const float2* __restrict__ tw,
        float2* __restrict__ Xh, float2* __restrict__ Hh){
    __shared__ float2 sc[M];
    const int t = threadIdx.x;
    const int sig = blockIdx.x;
    const float* srow;
    float2* dp;
    if (sig < B*CIN){ srow = x + (size_t)sig*T;        dp = Xh + (size_t)sig*JS; }
    else            { srow = H + (size_t)(sig-B*CIN)*T; dp = Hh + (size_t)(sig-B*CIN)*JS; }
    const float2* zp = (const float2*)srow;            // z[n] = x[2n] + i x[2n+1]
    float2 q[8];
    #pragma unroll
    for (int l = 0; l < 8; ++l) q[l] = zp[t + 512*l];
    dif_group8<512,1>(q, t, tw);
    lds_store8(sc, q, t, 512);
    __syncthreads();                                   // cross-wave regroup
    {
        const int base = ((t>>6)<<9) | (t&63);         // 512-pt chunk of wave t>>6
        lds_load8(sc, q, base, 64);
        dif_group8<64,4>(q, t&63, tw);
        lds_store8(sc, q, base, 64);
    }
    // no barrier: S=8 group stays in the same wave-owned 512-pt chunk
    {
        const int base = ((t>>3)<<6) | (t&7);
        lds_load8(sc, q, base, 8);
        dif_group8<8,7>(q, t&7, tw);
        lds_store8(sc, q, base, 8);
    }
    // no barrier: S=1 group is thread/wave-local
    {
        const int base = t << 3;
        lds_load8(sc, q, base, 1);
        dif_group8<1,10>(q, 0, tw);
        lds_store8(sc, q, base, 1);
    }
    __syncthreads();                                   // split reads cross-chunk pairs
    // Hermitian split: X[k] = E + w_k*O; Zm = Z[M-k]
    #pragma unroll
    for (int l = 0; l < 8; ++l){
        const int j  = t + 512*l;
        const int k  = brev12(j);
        const int j2 = brev12((M - k) & (M-1));
        float2 Z  = sc[swz(j)];
        float2 Zm = sc[swz(j2)];
        float2 E = make_float2(0.5f*(Z.x + Zm.x), 0.5f*(Z.y - Zm.y));
        float2 D = make_float2(Z.x - Zm.x, Z.y + Zm.y);        // Z - conj(Zm)
        float2 O = make_float2(0.5f*D.y, -0.5f*D.x);           // -i/2 * D
        dp[j] = cadd(E, cmul(tw[k], O));
        if (j == 0) dp[M] = make_float2(Z.x - Z.y, 0.0f);      // X[M] = ReZ0 - ImZ0
    }
}

// irfft: half-spectrum (packed layout) -> real row, *1/M + bias fused.
// Barriers: 3 (S=1,8,64 groups wave-local; only the S=512 group crosses waves).
__global__ __launch_bounds__(512) void irfft_out(const float2* __restrict__ Yh,
        const float2* __restrict__ tw, const float* __restrict__ bias, float* __restrict__ out){
    __shared__ float2 sc[M];
    const int t = threadIdx.x;
    const int sig = blockIdx.x;
    const float2* yp = Yh + (size_t)sig*JS;
    #pragma unroll
    for (int l = 0; l < 8; ++l){
        const int j = t + 512*l;
        sc[swz(j)] = yp[j];
    }
    float2 yM = yp[M];
    __syncthreads();
    // Hermitian combine, even-j owners only (k = brev12(j) < 2048), 4 full iterations:
    // Z[k] = E + i*O, Z[M-k] = conj(E) + i*conj(O);  pair positions (even j, odd j2) disjoint.
    #pragma unroll
    for (int l = 0; l < 4; ++l){
        const int j = (t + 512*l) << 1;                        // even j
        const int k = brev12(j);                               // k < 2048
        float2 Ym; int j2 = 0;
        if (k == 0){ Ym = yM; }
        else { j2 = brev12(M - k); Ym = sc[swz(j2)]; }
        float2 Y = sc[swz(j)];
        float2 E = make_float2(0.5f*(Y.x + Ym.x), 0.5f*(Y.y - Ym.y));
        float2 D = make_float2(0.5f*(Y.x - Ym.x), 0.5f*(Y.y + Ym.y));   // (Y - conj(Ym))/2
        float2 O = cmulc(D, tw[k]);
        sc[swz(j)] = make_float2(E.x - O.y, E.y + O.x);                 // Z[k]
        if (k != 0){
            sc[swz(j2)] = make_float2(E.x + O.y, O.x - E.y);            // Z[M-k]
        }
    }
    if (t == 0){   // j=1 <-> k=2048 self-paired: Z[2048] = E + i*O with Ym = Y
        float2 Y = sc[swz(1)];
        float2 E = make_float2(Y.x, 0.0f);
        float2 D = make_float2(0.0f, Y.y);
        float2 O = cmulc(D, tw[2048]);
        sc[swz(1)] = make_float2(E.x - O.y, E.y + O.x);
    }
    __syncthreads();
    float2 q[8];
    {
        const int base = t << 3;                       // thread-local 8-pt chunk
        lds_load8(sc, q, base, 1);
        dit_group8<1,12>(q, 0, tw);
        lds_store8(sc, q, base, 1);
    }
    // no barrier: S=8 group within wave-owned chunk
    {
        const int base = ((t>>3)<<6) | (t&7);
        lds_load8(sc, q, base, 8);
        dit_group8<8,9>(q, t&7, tw);
        lds_store8(sc, q, base, 8);
    }
    // no barrier: S=64 group within wave-owned 512-pt chunk
    {
        const int base = ((t>>6)<<9) | (t&63);
        lds_load8(sc, q, base, 64);
        dit_group8<64,6>(q, t&63, tw);
        lds_store8(sc, q, base, 64);
    }
    __syncthreads();                                   // S=512 group reads cross-wave
    lds_load8(sc, q, t, 512);
    dit_group8<512,3>(q, t, tw);        // final group fused to output
    const float scv = 1.0f/(float)M;
    const float bv = bias[sig & (COUT-1)];
    float2* op = (float2*)(out + (size_t)sig*T);
    #pragma unroll
    for (int l = 0; l < 8; ++l)
        op[t + 512*l] = make_float2(q[l].x*scv + bv, q[l].y*scv + bv);
}

// MLP hidden state H[h*T + t] + twiddle-table fill fused (blocks 0..15).
#define TB 32
__global__ __launch_bounds__(256) void mlp_hidden(const float* __restrict__ w1, const float* __restrict__ b1,
                           const float* __restrict__ w2, const float* __restrict__ b2,
                           float* __restrict__ H, float2* __restrict__ tw){
    __shared__ float sw1[HID], sb1[HID], sw2[HID*HID], sb2[HID];
    __shared__ float h1s[TB][HID+1];
    const int tid = threadIdx.x;
    if (blockIdx.x < 16){                       // fused tw_init: tw[k]=e^{-2pi i k/T}, k<4096
        const int k = blockIdx.x*256 + tid;
        float ang = -6.28318530717958647692f * (float)k / (float)T;
        float s, c;
        sincosf(ang, &s, &c);
        tw[k] = make_float2(c, s);
    }
    for (int i = tid; i < HID; i += 256){ sw1[i]=w1[i]; sb1[i]=b1[i]; sb2[i]=b2[i]; }
    for (int i = tid; i < HID*HID; i += 256) sw2[i]=w2[i];
    __syncthreads();
    const int t0 = blockIdx.x * TB;
    for (int e = tid; e < TB*HID; e += 256){
        const int tl = e & (TB-1), h = e >> 5;
        const float pos = (float)(t0 + tl) / (float)(T-1);
        h1s[tl][h] = gelu_exact(pos*sw1[h] + sb1[h]);
    }
    __syncthreads();
    const int tl = tid & (TB-1), hg = tid >> 5;   // hg 0..7
    float acc[8];
    #pragma unroll
    for (int u = 0; u < 8; ++u) acc[u] = sb2[hg*8 + u];
    for (int k = 0; k < HID; ++k){
        const float hv = h1s[tl][k];
        const float4 wa = *(const float4*)&sw2[k*HID + hg*8];
        const float4 wb = *(const float4*)&sw2[k*HID + hg*8 + 4];
        acc[0] += hv*wa.x; acc[1] += hv*wa.y; acc[2] += hv*wa.z; acc[3] += hv*wa.w;
        acc[4] += hv*wb.x; acc[5] += hv*wb.y; acc[6] += hv*wb.z; acc[7] += hv*wb.w;
    }
    #pragma unroll
    for (int u = 0; u < 8; ++u)
        H[(size_t)(hg*8 + u)*T + t0 + tl] = gelu_exact(acc[u]);
}

// Fused filter-spectrum GEMM + channel contraction over packed half-spectra.
// grid = (1025, 2): 4 j-columns x o-half. Conflict-engineered SoA LDS (~25.5 KB -> 6 blocks/CU).
__global__ __launch_bounds__(256) void filt_contract(const float* __restrict__ w3,
        const float* __restrict__ b3, const float2* __restrict__ Hh,
        const float2* __restrict__ Xh, float2* __restrict__ Yh){
    __shared__ float XsRe[CIN][FT][B+1];    // [i][f][b] pad 9: phase-B bank 4i+9f+b -> free
    __shared__ float XsIm[CIN][FT][B+1];
    __shared__ float FltRe[FT][16][33];     // [f][oL][i] pad 33: stores & reads <=2-way (free)
    __shared__ float FltIm[FT][16][33];
    const int t = threadIdx.x;
    const int f0 = blockIdx.x * FT;
    const int oh = blockIdx.y;              // o-half: o in [oh*16, oh*16+16)
    {
        const float4* xp4 = (const float4*)(Xh + (size_t)t*JS + f0);
        float4 u0 = xp4[0], u1 = xp4[1];
        const int b = t >> 5, i = t & 31;
        XsRe[i][0][b] = u0.x; XsIm[i][0][b] = u0.y;
        XsRe[i][1][b] = u0.z; XsIm[i][1][b] = u0.w;
        XsRe[i][2][b] = u1.x; XsIm[i][2][b] = u1.y;
        XsRe[i][3][b] = u1.z; XsIm[i][3][b] = u1.w;
    }
    // phase A: 2 oi per thread (oiG = oh*512 + 2t, 2t+1)
    const int oiG = oh*512 + (t << 1);
    float2 acc[2][FT];
    #pragma unroll
    for (int ii = 0; ii < 2; ++ii)
        #pragma unroll
        for (int f = 0; f < FT; ++f) acc[ii][f] = make_float2(0.f, 0.f);
    #pragma unroll 4
    for (int h = 0; h < HID; ++h){
        const float2 w2v = *(const float2*)(w3 + (size_t)h*(CIN*COUT) + oiG);  // coalesced
        const float2* hp = Hh + (size_t)h*JS + f0;                             // block-uniform
        float2 h0 = hp[0], h1 = hp[1], h2 = hp[2], h3 = hp[3];
        const float wv[2] = {w2v.x, w2v.y};
        #pragma unroll
        for (int ii = 0; ii < 2; ++ii){
            acc[ii][0].x += wv[ii]*h0.x; acc[ii][0].y += wv[ii]*h0.y;
            acc[ii][1].x += wv[ii]*h1.x; acc[ii][1].y += wv[ii]*h1.y;
            acc[ii][2].x += wv[ii]*h2.x; acc[ii][2].y += wv[ii]*h2.y;
            acc[ii][3].x += wv[ii]*h3.x; acc[ii][3].y += wv[ii]*h3.y;
        }
    }
    if (f0 == 0){   // DC: filter spectrum += T*b3
        #pragma unroll
        for (int ii = 0; ii < 2; ++ii)
            acc[ii][0].x += (float)T * b3[oiG + ii];
    }
    {
        const int oL = t >> 4;
        const int ib = (t & 15) << 1;
        #pragma unroll
        for (int ii = 0; ii < 2; ++ii)
            #pragma unroll
            for (int f = 0; f < FT; ++f){
                FltRe[f][oL][ib + ii] = acc[ii][f].x;
                FltIm[f][oL][ib + ii] = acc[ii][f].y;
            }
    }
    __syncthreads();
    // phase B: thread = (o2 = t>>4, f2 = (t>>2)&3, g = t&3); batches b = 2g+j
    const int o2 = t >> 4, f2 = (t >> 2) & 3, g = t & 3;
    float2 y[2];
    y[0] = make_float2(0.f, 0.f); y[1] = make_float2(0.f, 0.f);
    #pragma unroll 8
    for (int i0 = 0; i0 < CIN; ++i0){
        const float2 fv = make_float2(FltRe[f2][o2][i0], FltIm[f2][o2][i0]);
        #pragma unroll
        for (int j = 0; j < 2; ++j){
            const int b = (g << 1) | j;
            const float2 xv = make_float2(XsRe[i0][f2][b], XsIm[i0][f2][b]);
            y[j].x += xv.x*fv.x - xv.y*fv.y;
            y[j].y += xv.x*fv.y + xv.y*fv.x;
        }
    }
    if (f0 + f2 <= M){
        #pragma unroll
        for (int j = 0; j < 2; ++j){
            const int b = (g << 1) | j;
            const int o = oh*16 + o2;
            Yh[((size_t)(b*COUT + o))*JS + f0 + f2] = y[j];
        }
    }
}

extern "C" void kernel_launch(void* const* d_in, const int* in_sizes, int n_in,
                              void* d_out, int out_size, void* d_ws, size_t ws_size,
                              hipStream_t stream){
    const float* x    = (const float*)d_in[0];
    const float* w1   = (const float*)d_in[1];
    const float* b1   = (const float*)d_in[2];
    const float* w2   = (const float*)d_in[3];
    const float* b2   = (const float*)d_in[4];
    const float* w3   = (const float*)d_in[5];
    const float* b3   = (const float*)d_in[6];
    const float* bias = (const float*)d_in[7];
    float* out = (float*)d_out;

    // Workspace: Xh 8.5MB | Yh 8.5MB | Hh 2.2MB | H 2MB | tw 32KB  (~24 MB)
    char* ws = (char*)d_ws;
    float2* Xh = (float2*)ws;
    float2* Yh = (float2*)(ws + (size_t)9*1024*1024);
    float2* Hh = (float2*)(ws + (size_t)18*1024*1024);
    float*  H  = (float*) (ws + (size_t)21*1024*1024);
    float2* tws= (float2*)(ws + (size_t)23*1024*1024);

    hipLaunchKernelGGL(mlp_hidden,    dim3(T/TB),      dim3(256), 0, stream, w1, b1, w2, b2, H, tws);
    hipLaunchKernelGGL(rfft_all,      dim3(B*CIN+HID), dim3(512), 0, stream, x, H, tws, Xh, Hh);
    hipLaunchKernelGGL(filt_contract, dim3(M/FT + 1, 2), dim3(256), 0, stream, w3, b3, Hh, Xh, Yh);
    hipLaunchKernelGGL(irfft_out,     dim3(B*COUT),    dim3(512), 0, stream, Yh, tws, bias, out);
}